// Round 1
// baseline (511.205 us; speedup 1.0000x reference)
//
#include <hip/hip_runtime.h>
#include <hip/hip_bf16.h>
#include <cmath>
#include <cstdint>

typedef __bf16 bf16;
typedef __bf16 bf16x8 __attribute__((ext_vector_type(8)));
typedef __bf16 bf16x4 __attribute__((ext_vector_type(4)));
typedef float  f32x4  __attribute__((ext_vector_type(4)));

#define EMBED 1024
#define FFDIM 4096
#define BATCH 4
#define SEQ   2048
#define MTOK  (BATCH*SEQ)

// ---------------- workspace layout (byte offsets) ----------------
// total ~246 MB with reuse
static constexpr size_t OFF_XPE_F32 = 0;              // 32MB f32 [8192][1024]
static constexpr size_t OFF_XPE_B   = 32ull << 20;    // 16MB bf16 [8192][1024]; reused as h_bf16
static constexpr size_t OFF_Q       = 48ull << 20;    // 16MB bf16; Q..K region reused as P (32MB)
static constexpr size_t OFF_K       = 64ull << 20;    // 16MB bf16
static constexpr size_t OFF_VT      = 80ull << 20;    // 16MB bf16 [4][1024][2048]
static constexpr size_t OFF_E       = 96ull << 20;    // 64MB f32 [4][2048][2048]; reused as T1 bf16 [8192][4096]
static constexpr size_t OFF_ATTN    = 160ull << 20;   // 32MB f32; reused as Y f32
static constexpr size_t OFF_H       = 192ull << 20;   // 32MB f32
static constexpr size_t OFF_WQT     = 224ull << 20;   // 2MB bf16 [1024][1024]
static constexpr size_t OFF_WKT     = 226ull << 20;
static constexpr size_t OFF_WVT     = 228ull << 20;
static constexpr size_t OFF_W1T     = 230ull << 20;   // 8MB bf16 [4096][1024]
static constexpr size_t OFF_W2T     = 238ull << 20;   // 8MB bf16 [1024][4096]

// ---------------- PE add: xpe = x + sinusoidal_pe ----------------
__global__ __launch_bounds__(256) void pe_add_kernel(const float* __restrict__ x,
                                                     float* __restrict__ xf,
                                                     bf16* __restrict__ xb) {
  int idx  = blockIdx.x * 256 + threadIdx.x;   // SEQ*512 threads
  int pair = idx & 511;
  int s    = idx >> 9;
  float div = __expf((float)(2 * pair) * (-9.210340371976184f / (float)EMBED));
  float ang = (float)s * div;
  float sv = sinf(ang), cv = cosf(ang);
#pragma unroll
  for (int b = 0; b < BATCH; ++b) {
    size_t base = ((size_t)(b * SEQ + s)) * EMBED + (size_t)pair * 2;
    float v0 = x[base] + sv;
    float v1 = x[base + 1] + cv;
    xf[base] = v0; xf[base + 1] = v1;
    xb[base] = (bf16)v0; xb[base + 1] = (bf16)v1;
  }
}

// ---------------- weight transpose fp32[K][N] -> bf16[N][K] ----------------
__global__ __launch_bounds__(256) void transpose_kernel(const float* __restrict__ W,
                                                        bf16* __restrict__ Wt,
                                                        int K, int N) {
  __shared__ float tile[32][33];
  int nb = blockIdx.x * 32, kb = blockIdx.y * 32;
  int tx = threadIdx.x, ty = threadIdx.y;   // 32x8
#pragma unroll
  for (int i = 0; i < 32; i += 8)
    tile[ty + i][tx] = W[(size_t)(kb + ty + i) * N + nb + tx];
  __syncthreads();
#pragma unroll
  for (int i = 0; i < 32; i += 8)
    Wt[(size_t)(nb + ty + i) * K + kb + tx] = (bf16)tile[tx][ty + i];
}

// ---------------- GEMM: C[M,N] = A[M,K] @ Bt[N,K]^T, bf16 in, fp32 acc ----------------
// EPI 0: bf16 out, +bias (row-major)
// EPI 1: bf16 out, +bias, scatter-transposed to VT[b][col][s]  (V projection)
// EPI 2: f32 out, *scale (QK^T / PV)
// EPI 3: bf16 out, +bias, relu (FF1)
// EPI 4: f32 out, +bias (FF2)
#define BM 128
#define BN 128
#define BK 64

__device__ __forceinline__ void gload_lds16(const void* g, void* l) {
  __builtin_amdgcn_global_load_lds((const __attribute__((address_space(1))) void*)g,
                                   (__attribute__((address_space(3))) void*)l, 16, 0, 0);
}

template <int EPI>
__global__ __launch_bounds__(256) void gemm_kernel(
    const bf16* __restrict__ A, const bf16* __restrict__ B,
    const float* __restrict__ bias, void* __restrict__ out,
    int K, int ldo, long long sAz, long long sBz, long long sOz, float scale) {
  __shared__ __align__(16) bf16 sA[BM][BK];
  __shared__ __align__(16) bf16 sB[BN][BK];
  const int z = blockIdx.z;
  A += (size_t)z * sAz;
  B += (size_t)z * sBz;
  const int tid  = threadIdx.x;
  const int wave = tid >> 6;
  const int lane = tid & 63;
  const int wm = wave >> 1, wn = wave & 1;
  const int rowBase = blockIdx.y * BM;
  const int colBase = blockIdx.x * BN;

  // staging: chunk = p*256 + tid covers row (p*32 + tid>>3), elems ((tid&7)*8 .. +8)
  const int rA = tid >> 3;
  const int cL = (tid & 7) * 8;
  const bf16* gA = A + (size_t)(rowBase + rA) * K + cL;
  const bf16* gB = B + (size_t)(colBase + rA) * K + cL;
  char* lA = (char*)&sA[0][0] + wave * 1024;   // + p*4096, lane*16 added by HW
  char* lB = (char*)&sB[0][0] + wave * 1024;

  const f32x4 zero4 = {0.f, 0.f, 0.f, 0.f};
  f32x4 acc[4][4];
#pragma unroll
  for (int i = 0; i < 4; ++i)
#pragma unroll
    for (int j = 0; j < 4; ++j) acc[i][j] = zero4;

  const int lr = lane & 15;
  const int lk = (lane >> 4) * 8;

  for (int kt = 0; kt < K; kt += BK) {
#pragma unroll
    for (int p = 0; p < 4; ++p) {
      gload_lds16(gA + (size_t)(p * 32) * K + kt, lA + p * 4096);
      gload_lds16(gB + (size_t)(p * 32) * K + kt, lB + p * 4096);
    }
    __syncthreads();   // compiler emits vmcnt(0) drain before barrier
#pragma unroll
    for (int kk = 0; kk < 2; ++kk) {
      bf16x8 fa[4], fb[4];
#pragma unroll
      for (int i = 0; i < 4; ++i)
        fa[i] = *(const bf16x8*)&sA[wm * 64 + i * 16 + lr][kk * 32 + lk];
#pragma unroll
      for (int j = 0; j < 4; ++j)
        fb[j] = *(const bf16x8*)&sB[wn * 64 + j * 16 + lr][kk * 32 + lk];
#pragma unroll
      for (int i = 0; i < 4; ++i)
#pragma unroll
        for (int j = 0; j < 4; ++j)
          acc[i][j] = __builtin_amdgcn_mfma_f32_16x16x32_bf16(fa[i], fb[j], acc[i][j], 0, 0, 0);
    }
    __syncthreads();
  }

  // epilogue: C/D layout col = lane&15, row = (lane>>4)*4 + reg   [m89-verified]
  const int lrow4 = (lane >> 4) * 4;
#pragma unroll
  for (int j = 0; j < 4; ++j) {
    const int col = colBase + wn * 64 + j * 16 + lr;
    float bv = 0.f;
    if constexpr (EPI == 0 || EPI == 1 || EPI == 3 || EPI == 4) bv = bias[col];
#pragma unroll
    for (int i = 0; i < 4; ++i) {
      const int row0 = rowBase + wm * 64 + i * 16 + lrow4;
      if constexpr (EPI == 1) {
        // 4 consecutive s positions at fixed (b, col): pack into one 8B store
        const int b_ = row0 >> 11;
        const int s_ = row0 & (SEQ - 1);
        bf16x4 pv;
#pragma unroll
        for (int r = 0; r < 4; ++r) pv[r] = (bf16)(acc[i][j][r] + bv);
        *(bf16x4*)((bf16*)out + ((size_t)b_ * EMBED + col) * SEQ + s_) = pv;
      } else {
#pragma unroll
        for (int r = 0; r < 4; ++r) {
          const int row = row0 + r;
          const float v = acc[i][j][r];
          if constexpr (EPI == 0) {
            ((bf16*)out)[(size_t)z * sOz + (size_t)row * ldo + col] = (bf16)(v + bv);
          } else if constexpr (EPI == 2) {
            ((float*)out)[(size_t)z * sOz + (size_t)row * ldo + col] = v * scale;
          } else if constexpr (EPI == 3) {
            float t = v + bv;
            ((bf16*)out)[(size_t)row * ldo + col] = (bf16)(t > 0.f ? t : 0.f);
          } else if constexpr (EPI == 4) {
            ((float*)out)[(size_t)row * ldo + col] = v + bv;
          }
        }
      }
    }
  }
}

// ---------------- row softmax: E f32 [rows][SEQ] -> P bf16 ----------------
__global__ __launch_bounds__(256) void softmax_kernel(const float* __restrict__ E,
                                                      bf16* __restrict__ P) {
  const size_t row = blockIdx.x;
  const float* e = E + row * SEQ;
  const int t = threadIdx.x;
  float4 a = ((const float4*)e)[2 * t];
  float4 b = ((const float4*)e)[2 * t + 1];
  float m = fmaxf(fmaxf(fmaxf(a.x, a.y), fmaxf(a.z, a.w)),
                  fmaxf(fmaxf(b.x, b.y), fmaxf(b.z, b.w)));
#pragma unroll
  for (int o = 32; o; o >>= 1) m = fmaxf(m, __shfl_xor(m, o));
  __shared__ float red[8];
  const int w = t >> 6;
  if ((t & 63) == 0) red[w] = m;
  __syncthreads();
  m = fmaxf(fmaxf(red[0], red[1]), fmaxf(red[2], red[3]));
  float ex[8];
  ex[0] = __expf(a.x - m); ex[1] = __expf(a.y - m);
  ex[2] = __expf(a.z - m); ex[3] = __expf(a.w - m);
  ex[4] = __expf(b.x - m); ex[5] = __expf(b.y - m);
  ex[6] = __expf(b.z - m); ex[7] = __expf(b.w - m);
  float s = ex[0] + ex[1] + ex[2] + ex[3] + ex[4] + ex[5] + ex[6] + ex[7];
#pragma unroll
  for (int o = 32; o; o >>= 1) s += __shfl_xor(s, o);
  if ((t & 63) == 0) red[4 + w] = s;
  __syncthreads();
  s = red[4] + red[5] + red[6] + red[7];
  const float inv = 1.0f / s;
  bf16x8 pv;
#pragma unroll
  for (int q = 0; q < 8; ++q) pv[q] = (bf16)(ex[q] * inv);
  *(bf16x8*)(P + row * SEQ + (size_t)t * 8) = pv;
}

// ---------------- LayerNorm: out = LN(X + R) * g + b ----------------
__global__ __launch_bounds__(256) void ln_kernel(const float* __restrict__ X,
                                                 const float* __restrict__ R,
                                                 const float* __restrict__ gm,
                                                 const float* __restrict__ bt,
                                                 float* __restrict__ of,
                                                 bf16* __restrict__ ob) {
  const size_t row = blockIdx.x;
  const int t = threadIdx.x;
  float4 xv = ((const float4*)(X + row * EMBED))[t];
  float4 rv = ((const float4*)(R + row * EMBED))[t];
  float4 v;
  v.x = xv.x + rv.x; v.y = xv.y + rv.y; v.z = xv.z + rv.z; v.w = xv.w + rv.w;
  float s  = v.x + v.y + v.z + v.w;
  float ss = v.x * v.x + v.y * v.y + v.z * v.z + v.w * v.w;
#pragma unroll
  for (int o = 32; o; o >>= 1) { s += __shfl_xor(s, o); ss += __shfl_xor(ss, o); }
  __shared__ float red[8];
  const int w = t >> 6;
  if ((t & 63) == 0) { red[w] = s; red[4 + w] = ss; }
  __syncthreads();
  s  = red[0] + red[1] + red[2] + red[3];
  ss = red[4] + red[5] + red[6] + red[7];
  const float mu  = s * (1.0f / EMBED);
  const float inv = rsqrtf(ss * (1.0f / EMBED) - mu * mu + 1e-5f);
  float4 gv = ((const float4*)gm)[t];
  float4 bv = ((const float4*)bt)[t];
  float4 o4;
  o4.x = (v.x - mu) * inv * gv.x + bv.x;
  o4.y = (v.y - mu) * inv * gv.y + bv.y;
  o4.z = (v.z - mu) * inv * gv.z + bv.z;
  o4.w = (v.w - mu) * inv * gv.w + bv.w;
  if (of) ((float4*)(of + row * EMBED))[t] = o4;
  if (ob) {
    bf16x4 p;
    p[0] = (bf16)o4.x; p[1] = (bf16)o4.y; p[2] = (bf16)o4.z; p[3] = (bf16)o4.w;
    *(bf16x4*)(ob + row * EMBED + (size_t)t * 4) = p;
  }
}

// ---------------- launch ----------------
extern "C" void kernel_launch(void* const* d_in, const int* in_sizes, int n_in,
                              void* d_out, int out_size, void* d_ws, size_t ws_size,
                              hipStream_t stream) {
  const float* x   = (const float*)d_in[0];
  const float* Wq  = (const float*)d_in[1];
  const float* bq  = (const float*)d_in[2];
  const float* Wk  = (const float*)d_in[3];
  const float* bk  = (const float*)d_in[4];
  const float* Wv  = (const float*)d_in[5];
  const float* bv  = (const float*)d_in[6];
  const float* W1  = (const float*)d_in[7];
  const float* b1  = (const float*)d_in[8];
  const float* W2  = (const float*)d_in[9];
  const float* b2  = (const float*)d_in[10];
  const float* g1  = (const float*)d_in[11];
  const float* be1 = (const float*)d_in[12];
  const float* g2  = (const float*)d_in[13];
  const float* be2 = (const float*)d_in[14];
  float* out = (float*)d_out;
  char* ws = (char*)d_ws;

  float* xpe  = (float*)(ws + OFF_XPE_F32);
  bf16*  xpeb = (bf16*)(ws + OFF_XPE_B);
  bf16*  Qb   = (bf16*)(ws + OFF_Q);
  bf16*  Kb   = (bf16*)(ws + OFF_K);
  bf16*  VT   = (bf16*)(ws + OFF_VT);
  float* E    = (float*)(ws + OFF_E);
  bf16*  P    = (bf16*)(ws + OFF_Q);     // reuse Q+K region
  float* attn = (float*)(ws + OFF_ATTN);
  float* h    = (float*)(ws + OFF_H);
  bf16*  hb   = (bf16*)(ws + OFF_XPE_B); // reuse xpe_bf16 region
  bf16*  T1   = (bf16*)(ws + OFF_E);     // reuse energy region
  float* Y    = (float*)(ws + OFF_ATTN); // reuse attn region
  bf16*  WqT  = (bf16*)(ws + OFF_WQT);
  bf16*  WkT  = (bf16*)(ws + OFF_WKT);
  bf16*  WvT  = (bf16*)(ws + OFF_WVT);
  bf16*  W1T  = (bf16*)(ws + OFF_W1T);
  bf16*  W2T  = (bf16*)(ws + OFF_W2T);

  const dim3 tb(32, 8);
  transpose_kernel<<<dim3(EMBED / 32, EMBED / 32), tb, 0, stream>>>(Wq, WqT, EMBED, EMBED);
  transpose_kernel<<<dim3(EMBED / 32, EMBED / 32), tb, 0, stream>>>(Wk, WkT, EMBED, EMBED);
  transpose_kernel<<<dim3(EMBED / 32, EMBED / 32), tb, 0, stream>>>(Wv, WvT, EMBED, EMBED);
  transpose_kernel<<<dim3(FFDIM / 32, EMBED / 32), tb, 0, stream>>>(W1, W1T, EMBED, FFDIM);
  transpose_kernel<<<dim3(EMBED / 32, FFDIM / 32), tb, 0, stream>>>(W2, W2T, FFDIM, EMBED);

  pe_add_kernel<<<(SEQ * 512) / 256, 256, 0, stream>>>(x, xpe, xpeb);

  // QKV projections
  gemm_kernel<0><<<dim3(EMBED / BN, MTOK / BM, 1), 256, 0, stream>>>(
      xpeb, WqT, bq, Qb, EMBED, EMBED, 0, 0, 0, 1.0f);
  gemm_kernel<0><<<dim3(EMBED / BN, MTOK / BM, 1), 256, 0, stream>>>(
      xpeb, WkT, bk, Kb, EMBED, EMBED, 0, 0, 0, 1.0f);
  gemm_kernel<1><<<dim3(EMBED / BN, MTOK / BM, 1), 256, 0, stream>>>(
      xpeb, WvT, bv, VT, EMBED, 0, 0, 0, 0, 1.0f);

  // energy = Q @ K^T / 32   (batched)
  gemm_kernel<2><<<dim3(SEQ / BN, SEQ / BM, BATCH), 256, 0, stream>>>(
      Qb, Kb, nullptr, E, EMBED, SEQ,
      (long long)SEQ * EMBED, (long long)SEQ * EMBED, (long long)SEQ * SEQ, 0.03125f);

  softmax_kernel<<<BATCH * SEQ, 256, 0, stream>>>(E, P);

  // attn_out = P @ V  (batched, VT is [EMBED][SEQ] per batch)
  gemm_kernel<2><<<dim3(EMBED / BN, SEQ / BM, BATCH), 256, 0, stream>>>(
      P, VT, nullptr, attn, SEQ, EMBED,
      (long long)SEQ * SEQ, (long long)EMBED * SEQ, (long long)SEQ * EMBED, 1.0f);

  // h = LN(attn + xpe)
  ln_kernel<<<MTOK, 256, 0, stream>>>(attn, xpe, g1, be1, h, hb);

  // FF1: relu(h @ W1 + b1)
  gemm_kernel<3><<<dim3(FFDIM / BN, MTOK / BM, 1), 256, 0, stream>>>(
      hb, W1T, b1, T1, EMBED, FFDIM, 0, 0, 0, 1.0f);
  // FF2: T1 @ W2 + b2
  gemm_kernel<4><<<dim3(EMBED / BN, MTOK / BM, 1), 256, 0, stream>>>(
      T1, W2T, b2, Y, FFDIM, EMBED, 0, 0, 0, 1.0f);

  // out = LN(Y + h)
  ln_kernel<<<MTOK, 256, 0, stream>>>(Y, h, g2, be2, out, nullptr);
}

// Round 2
// 437.380 us; speedup vs baseline: 1.1688x; 1.1688x over previous
//
#include <hip/hip_runtime.h>
#include <hip/hip_bf16.h>
#include <cmath>
#include <cstdint>

typedef __bf16 bf16;
typedef __bf16 bf16x8 __attribute__((ext_vector_type(8)));
typedef __bf16 bf16x4 __attribute__((ext_vector_type(4)));
typedef float  f32x4  __attribute__((ext_vector_type(4)));

#define EMBED 1024
#define FFDIM 4096
#define BATCH 4
#define SEQ   2048
#define MTOK  (BATCH*SEQ)

// ---------------- workspace layout (byte offsets) ----------------
static constexpr size_t OFF_XPE_F32 = 0;              // 32MB f32 [8192][1024]
static constexpr size_t OFF_XPE_B   = 32ull << 20;    // 16MB bf16; reused as h_bf16
static constexpr size_t OFF_Q       = 48ull << 20;    // 16MB bf16; Q..K region reused as P (32MB)
static constexpr size_t OFF_K       = 64ull << 20;    // 16MB bf16
static constexpr size_t OFF_VT      = 80ull << 20;    // 16MB bf16 [4][1024][2048]
static constexpr size_t OFF_E       = 96ull << 20;    // 64MB f32; reused as T1 bf16 [8192][4096]
static constexpr size_t OFF_ATTN    = 160ull << 20;   // 32MB f32; reused as Y f32
static constexpr size_t OFF_H       = 192ull << 20;   // 32MB f32
static constexpr size_t OFF_WQT     = 224ull << 20;   // 2MB bf16 [1024][1024]
static constexpr size_t OFF_WKT     = 226ull << 20;
static constexpr size_t OFF_WVT     = 228ull << 20;
static constexpr size_t OFF_W1T     = 230ull << 20;   // 8MB bf16 [4096][1024]
static constexpr size_t OFF_W2T     = 238ull << 20;   // 8MB bf16 [1024][4096]

// ---------------- PE add ----------------
__global__ __launch_bounds__(256) void pe_add_kernel(const float* __restrict__ x,
                                                     float* __restrict__ xf,
                                                     bf16* __restrict__ xb) {
  int idx  = blockIdx.x * 256 + threadIdx.x;
  int pair = idx & 511;
  int s    = idx >> 9;
  float div = __expf((float)(2 * pair) * (-9.210340371976184f / (float)EMBED));
  float ang = (float)s * div;
  float sv = sinf(ang), cv = cosf(ang);
#pragma unroll
  for (int b = 0; b < BATCH; ++b) {
    size_t base = ((size_t)(b * SEQ + s)) * EMBED + (size_t)pair * 2;
    float v0 = x[base] + sv;
    float v1 = x[base + 1] + cv;
    xf[base] = v0; xf[base + 1] = v1;
    xb[base] = (bf16)v0; xb[base + 1] = (bf16)v1;
  }
}

// ---------------- weight transpose fp32[K][N] -> bf16[N][K] ----------------
__global__ __launch_bounds__(256) void transpose_kernel(const float* __restrict__ W,
                                                        bf16* __restrict__ Wt,
                                                        int K, int N) {
  __shared__ float tile[32][33];
  int nb = blockIdx.x * 32, kb = blockIdx.y * 32;
  int tx = threadIdx.x, ty = threadIdx.y;   // 32x8
#pragma unroll
  for (int i = 0; i < 32; i += 8)
    tile[ty + i][tx] = W[(size_t)(kb + ty + i) * N + nb + tx];
  __syncthreads();
#pragma unroll
  for (int i = 0; i < 32; i += 8)
    Wt[(size_t)(nb + ty + i) * K + kb + tx] = (bf16)tile[tx][ty + i];
}

// ---------------- GEMM: C[M,N] = A[M,K] @ Bt[N,K]^T, bf16 in, fp32 acc ----------------
// EPI 0: bf16 out, +bias            EPI 1: bf16 out, +bias, scatter->VT
// EPI 2: f32 out, *scale            EPI 3: bf16 out, +bias, relu
// EPI 4: f32 out, +bias
#define BM 128
#define BN 128
#define BK 64

__device__ __forceinline__ void gload_lds16(const void* g, void* l) {
  __builtin_amdgcn_global_load_lds((const __attribute__((address_space(1))) void*)g,
                                   (__attribute__((address_space(3))) void*)l, 16, 0, 0);
}

template <int EPI>
__global__ __launch_bounds__(256) void gemm_kernel(
    const bf16* __restrict__ A, const bf16* __restrict__ B,
    const float* __restrict__ bias, void* __restrict__ out,
    int K, int ldo, long long sAz, long long sBz, long long sOz, float scale) {
  __shared__ __align__(16) bf16 sA[BM][BK];
  __shared__ __align__(16) bf16 sB[BN][BK];

  // ---- T1: bijective XCD-chunked swizzle (m204) + grouped raster ----
  const int gx = gridDim.x, gy = gridDim.y;
  {
    // nothing; computed below
  }
  int id = blockIdx.x + gx * (blockIdx.y + gy * blockIdx.z);
  const int n  = gx * gy * gridDim.z;
  const int q  = n >> 3, r = n & 7;
  const int xcd = id & 7, pos = id >> 3;
  int lid = (xcd < r ? xcd * (q + 1) : r * (q + 1) + (xcd - r) * q) + pos;
  const int per = gx * gy;
  const int tz = lid / per;
  int s2 = lid - tz * per;
  const int G = 16;
  const int ngrp = G * gy;
  const int grp = s2 / ngrp;
  const int within = s2 - grp * ngrp;
  const int gw = min(G, gx - grp * G);
  const int tx = grp * G + within % gw;
  const int ty = within / gw;

  A += (size_t)tz * sAz;
  B += (size_t)tz * sBz;
  const int tid  = threadIdx.x;
  const int wave = tid >> 6;
  const int lane = tid & 63;
  const int wm = wave >> 1, wn = wave & 1;
  const int rowBase = ty * BM;
  const int colBase = tx * BN;

  // staging: chunk p*256+tid covers LDS row (p*32 + tid>>3), slot (tid&7)
  // T2: LDS(row, slot) must hold global slot (slot ^ (row&7))  [rule 21]
  const int rA = tid >> 3;
  const int srcSlot = (tid & 7) ^ (rA & 7);
  const bf16* gA = A + (size_t)(rowBase + rA) * K + srcSlot * 8;
  const bf16* gB = B + (size_t)(colBase + rA) * K + srcSlot * 8;
  char* lA = (char*)&sA[0][0] + wave * 1024;   // + p*4096, lane*16 added by HW
  char* lB = (char*)&sB[0][0] + wave * 1024;

  const f32x4 zero4 = {0.f, 0.f, 0.f, 0.f};
  f32x4 acc[4][4];
#pragma unroll
  for (int i = 0; i < 4; ++i)
#pragma unroll
    for (int j = 0; j < 4; ++j) acc[i][j] = zero4;

  const int lr = lane & 15;
  const int lx = lane & 7;     // == row&7 for fragment rows (offsets are mult of 8)
  const int q4 = lane >> 4;    // slot sub-index
  const char* bA = (const char*)&sA[0][0];
  const char* bB = (const char*)&sB[0][0];

  for (int kt = 0; kt < K; kt += BK) {
#pragma unroll
    for (int p = 0; p < 4; ++p) {
      gload_lds16(gA + (size_t)(p * 32) * K + kt, lA + p * 4096);
      gload_lds16(gB + (size_t)(p * 32) * K + kt, lB + p * 4096);
    }
    __syncthreads();
#pragma unroll
    for (int kk = 0; kk < 2; ++kk) {
      bf16x8 fa[4], fb[4];
      const int slot = kk * 4 + q4;
      const int sws = (slot ^ lx) << 4;
#pragma unroll
      for (int i = 0; i < 4; ++i)
        fa[i] = *(const bf16x8*)(bA + (wm * 64 + i * 16 + lr) * 128 + sws);
#pragma unroll
      for (int j = 0; j < 4; ++j)
        fb[j] = *(const bf16x8*)(bB + (wn * 64 + j * 16 + lr) * 128 + sws);
#pragma unroll
      for (int i = 0; i < 4; ++i)
#pragma unroll
        for (int j = 0; j < 4; ++j)
          acc[i][j] = __builtin_amdgcn_mfma_f32_16x16x32_bf16(fa[i], fb[j], acc[i][j], 0, 0, 0);
    }
    __syncthreads();
  }

  // epilogue: C/D layout col = lane&15, row = (lane>>4)*4 + reg   [m89-verified]
  const int lrow4 = (lane >> 4) * 4;
#pragma unroll
  for (int j = 0; j < 4; ++j) {
    const int col = colBase + wn * 64 + j * 16 + lr;
    float bv = 0.f;
    if constexpr (EPI == 0 || EPI == 1 || EPI == 3 || EPI == 4) bv = bias[col];
#pragma unroll
    for (int i = 0; i < 4; ++i) {
      const int row0 = rowBase + wm * 64 + i * 16 + lrow4;
      if constexpr (EPI == 1) {
        const int b_ = row0 >> 11;
        const int s_ = row0 & (SEQ - 1);
        bf16x4 pv;
#pragma unroll
        for (int r = 0; r < 4; ++r) pv[r] = (bf16)(acc[i][j][r] + bv);
        *(bf16x4*)((bf16*)out + ((size_t)b_ * EMBED + col) * SEQ + s_) = pv;
      } else {
#pragma unroll
        for (int r = 0; r < 4; ++r) {
          const int row = row0 + r;
          const float v = acc[i][j][r];
          if constexpr (EPI == 0) {
            ((bf16*)out)[(size_t)tz * sOz + (size_t)row * ldo + col] = (bf16)(v + bv);
          } else if constexpr (EPI == 2) {
            ((float*)out)[(size_t)tz * sOz + (size_t)row * ldo + col] = v * scale;
          } else if constexpr (EPI == 3) {
            float t = v + bv;
            ((bf16*)out)[(size_t)row * ldo + col] = (bf16)(t > 0.f ? t : 0.f);
          } else if constexpr (EPI == 4) {
            ((float*)out)[(size_t)row * ldo + col] = v + bv;
          }
        }
      }
    }
  }
}

// ---------------- row softmax: E f32 [rows][SEQ] -> P bf16 ----------------
__global__ __launch_bounds__(256) void softmax_kernel(const float* __restrict__ E,
                                                      bf16* __restrict__ P) {
  const size_t row = blockIdx.x;
  const float* e = E + row * SEQ;
  const int t = threadIdx.x;
  float4 a = ((const float4*)e)[2 * t];
  float4 b = ((const float4*)e)[2 * t + 1];
  float m = fmaxf(fmaxf(fmaxf(a.x, a.y), fmaxf(a.z, a.w)),
                  fmaxf(fmaxf(b.x, b.y), fmaxf(b.z, b.w)));
#pragma unroll
  for (int o = 32; o; o >>= 1) m = fmaxf(m, __shfl_xor(m, o));
  __shared__ float red[8];
  const int w = t >> 6;
  if ((t & 63) == 0) red[w] = m;
  __syncthreads();
  m = fmaxf(fmaxf(red[0], red[1]), fmaxf(red[2], red[3]));
  float ex[8];
  ex[0] = __expf(a.x - m); ex[1] = __expf(a.y - m);
  ex[2] = __expf(a.z - m); ex[3] = __expf(a.w - m);
  ex[4] = __expf(b.x - m); ex[5] = __expf(b.y - m);
  ex[6] = __expf(b.z - m); ex[7] = __expf(b.w - m);
  float s = ex[0] + ex[1] + ex[2] + ex[3] + ex[4] + ex[5] + ex[6] + ex[7];
#pragma unroll
  for (int o = 32; o; o >>= 1) s += __shfl_xor(s, o);
  if ((t & 63) == 0) red[4 + w] = s;
  __syncthreads();
  s = red[4] + red[5] + red[6] + red[7];
  const float inv = 1.0f / s;
  bf16x8 pv;
#pragma unroll
  for (int q = 0; q < 8; ++q) pv[q] = (bf16)(ex[q] * inv);
  *(bf16x8*)(P + row * SEQ + (size_t)t * 8) = pv;
}

// ---------------- LayerNorm: out = LN(X + R) * g + b ----------------
__global__ __launch_bounds__(256) void ln_kernel(const float* __restrict__ X,
                                                 const float* __restrict__ R,
                                                 const float* __restrict__ gm,
                                                 const float* __restrict__ bt,
                                                 float* __restrict__ of,
                                                 bf16* __restrict__ ob) {
  const size_t row = blockIdx.x;
  const int t = threadIdx.x;
  float4 xv = ((const float4*)(X + row * EMBED))[t];
  float4 rv = ((const float4*)(R + row * EMBED))[t];
  float4 v;
  v.x = xv.x + rv.x; v.y = xv.y + rv.y; v.z = xv.z + rv.z; v.w = xv.w + rv.w;
  float s  = v.x + v.y + v.z + v.w;
  float ss = v.x * v.x + v.y * v.y + v.z * v.z + v.w * v.w;
#pragma unroll
  for (int o = 32; o; o >>= 1) { s += __shfl_xor(s, o); ss += __shfl_xor(ss, o); }
  __shared__ float red[8];
  const int w = t >> 6;
  if ((t & 63) == 0) { red[w] = s; red[4 + w] = ss; }
  __syncthreads();
  s  = red[0] + red[1] + red[2] + red[3];
  ss = red[4] + red[5] + red[6] + red[7];
  const float mu  = s * (1.0f / EMBED);
  const float inv = rsqrtf(ss * (1.0f / EMBED) - mu * mu + 1e-5f);
  float4 gv = ((const float4*)gm)[t];
  float4 bv = ((const float4*)bt)[t];
  float4 o4;
  o4.x = (v.x - mu) * inv * gv.x + bv.x;
  o4.y = (v.y - mu) * inv * gv.y + bv.y;
  o4.z = (v.z - mu) * inv * gv.z + bv.z;
  o4.w = (v.w - mu) * inv * gv.w + bv.w;
  if (of) ((float4*)(of + row * EMBED))[t] = o4;
  if (ob) {
    bf16x4 p;
    p[0] = (bf16)o4.x; p[1] = (bf16)o4.y; p[2] = (bf16)o4.z; p[3] = (bf16)o4.w;
    *(bf16x4*)(ob + row * EMBED + (size_t)t * 4) = p;
  }
}

// ---------------- launch ----------------
extern "C" void kernel_launch(void* const* d_in, const int* in_sizes, int n_in,
                              void* d_out, int out_size, void* d_ws, size_t ws_size,
                              hipStream_t stream) {
  const float* x   = (const float*)d_in[0];
  const float* Wq  = (const float*)d_in[1];
  const float* bq  = (const float*)d_in[2];
  const float* Wk  = (const float*)d_in[3];
  const float* bk  = (const float*)d_in[4];
  const float* Wv  = (const float*)d_in[5];
  const float* bv  = (const float*)d_in[6];
  const float* W1  = (const float*)d_in[7];
  const float* b1  = (const float*)d_in[8];
  const float* W2  = (const float*)d_in[9];
  const float* b2  = (const float*)d_in[10];
  const float* g1  = (const float*)d_in[11];
  const float* be1 = (const float*)d_in[12];
  const float* g2  = (const float*)d_in[13];
  const float* be2 = (const float*)d_in[14];
  float* out = (float*)d_out;
  char* ws = (char*)d_ws;

  float* xpe  = (float*)(ws + OFF_XPE_F32);
  bf16*  xpeb = (bf16*)(ws + OFF_XPE_B);
  bf16*  Qb   = (bf16*)(ws + OFF_Q);
  bf16*  Kb   = (bf16*)(ws + OFF_K);
  bf16*  VT   = (bf16*)(ws + OFF_VT);
  float* E    = (float*)(ws + OFF_E);
  bf16*  P    = (bf16*)(ws + OFF_Q);     // reuse Q+K region
  float* attn = (float*)(ws + OFF_ATTN);
  float* h    = (float*)(ws + OFF_H);
  bf16*  hb   = (bf16*)(ws + OFF_XPE_B); // reuse xpe_bf16 region
  bf16*  T1   = (bf16*)(ws + OFF_E);     // reuse energy region
  float* Y    = (float*)(ws + OFF_ATTN); // reuse attn region
  bf16*  WqT  = (bf16*)(ws + OFF_WQT);
  bf16*  WkT  = (bf16*)(ws + OFF_WKT);
  bf16*  WvT  = (bf16*)(ws + OFF_WVT);
  bf16*  W1T  = (bf16*)(ws + OFF_W1T);
  bf16*  W2T  = (bf16*)(ws + OFF_W2T);

  const dim3 tb(32, 8);
  transpose_kernel<<<dim3(EMBED / 32, EMBED / 32), tb, 0, stream>>>(Wq, WqT, EMBED, EMBED);
  transpose_kernel<<<dim3(EMBED / 32, EMBED / 32), tb, 0, stream>>>(Wk, WkT, EMBED, EMBED);
  transpose_kernel<<<dim3(EMBED / 32, EMBED / 32), tb, 0, stream>>>(Wv, WvT, EMBED, EMBED);
  transpose_kernel<<<dim3(FFDIM / 32, EMBED / 32), tb, 0, stream>>>(W1, W1T, EMBED, FFDIM);
  transpose_kernel<<<dim3(EMBED / 32, FFDIM / 32), tb, 0, stream>>>(W2, W2T, FFDIM, EMBED);

  pe_add_kernel<<<(SEQ * 512) / 256, 256, 0, stream>>>(x, xpe, xpeb);

  // QKV projections
  gemm_kernel<0><<<dim3(EMBED / BN, MTOK / BM, 1), 256, 0, stream>>>(
      xpeb, WqT, bq, Qb, EMBED, EMBED, 0, 0, 0, 1.0f);
  gemm_kernel<0><<<dim3(EMBED / BN, MTOK / BM, 1), 256, 0, stream>>>(
      xpeb, WkT, bk, Kb, EMBED, EMBED, 0, 0, 0, 1.0f);
  gemm_kernel<1><<<dim3(EMBED / BN, MTOK / BM, 1), 256, 0, stream>>>(
      xpeb, WvT, bv, VT, EMBED, 0, 0, 0, 0, 1.0f);

  // energy = Q @ K^T / 32   (batched)
  gemm_kernel<2><<<dim3(SEQ / BN, SEQ / BM, BATCH), 256, 0, stream>>>(
      Qb, Kb, nullptr, E, EMBED, SEQ,
      (long long)SEQ * EMBED, (long long)SEQ * EMBED, (long long)SEQ * SEQ, 0.03125f);

  softmax_kernel<<<BATCH * SEQ, 256, 0, stream>>>(E, P);

  // attn_out = P @ V  (batched, VT is [EMBED][SEQ] per batch)
  gemm_kernel<2><<<dim3(EMBED / BN, SEQ / BM, BATCH), 256, 0, stream>>>(
      P, VT, nullptr, attn, SEQ, EMBED,
      (long long)SEQ * SEQ, (long long)EMBED * SEQ, (long long)SEQ * EMBED, 1.0f);

  // h = LN(attn + xpe)
  ln_kernel<<<MTOK, 256, 0, stream>>>(attn, xpe, g1, be1, h, hb);

  // FF1: relu(h @ W1 + b1)
  gemm_kernel<3><<<dim3(FFDIM / BN, MTOK / BM, 1), 256, 0, stream>>>(
      hb, W1T, b1, T1, EMBED, FFDIM, 0, 0, 0, 1.0f);
  // FF2: T1 @ W2 + b2
  gemm_kernel<4><<<dim3(EMBED / BN, MTOK / BM, 1), 256, 0, stream>>>(
      T1, W2T, b2, Y, FFDIM, EMBED, 0, 0, 0, 1.0f);

  // out = LN(Y + h)
  ln_kernel<<<MTOK, 256, 0, stream>>>(Y, h, g2, be2, out, nullptr);
}